// Round 11
// baseline (376.629 us; speedup 1.0000x reference)
//
#include <hip/hip_runtime.h>
#include <hip/hip_bf16.h>

// ---------------------------------------------------------------------------
// Swin WindowAttention fused kernel, v11: 85-VGPR diet -> 3 blocks/CU.
//   - __launch_bounds__(512,3): cap = 256/arg2 = 85 (law verified R2/R7/R8).
//     3 blocks x 8 waves = 24 static waves/CU (vs 16 in R3-R10) -> +50% TLP.
//   - Register diet vs v9 (96): PV runs AFTER the barrier writing xs direct
//     (ob park gone, -16); sbv add then smv add sequentially (-16); Q/K/V at
//     BK=32 2-wide (peak acc32+bb8+a16); V as two dt half-passes (acc 16,
//     pB 32 parked); proj BK=64 4-wide (po32+bw16+a32=80).
//   - No depth-2 pipeline (cost ~24 regs for +20us; TLP replaces it).
//   - Kept: 1 head/wave, phase order Q->K->scores->V->PV, identity-MFMA
//     transposes, swapped-operand scores, K=16 PV, sb/sm split tables,
//     setprio on attn MFMAs, LDS 32 KiB xs reused for attn-out.
// ---------------------------------------------------------------------------

#define NTOK 49
static constexpr float SCALE_Q = 0.17677669529663687f; // 32^-0.5

using bf16   = __bf16;
using bf16x4 = __attribute__((ext_vector_type(4))) __bf16;
using bf16x8 = __attribute__((ext_vector_type(8))) __bf16;
using short4v = __attribute__((ext_vector_type(4))) short;
using f32x4  = __attribute__((ext_vector_type(4))) float;

#define WT_QKV_OFF 0
#define WT_PROJ_OFF (768 * 256 * 2)
#define SB_OFF (WT_PROJ_OFF + 256 * 256 * 2)
#define SM_OFF (SB_OFF + 8 * 4096 * 4)
#define WS_NEEDED (SM_OFF + (size_t)64 * 4096 * 4)

// ---- 16x16x16 bf16 MFMA wrapper (builtin-name portability) ----
static __device__ __forceinline__ f32x4 mfma16(bf16x4 a, bf16x4 b, f32x4 c) {
#if __has_builtin(__builtin_amdgcn_mfma_f32_16x16x16_bf16)
    return __builtin_amdgcn_mfma_f32_16x16x16_bf16(a, b, c, 0, 0, 0);
#elif __has_builtin(__builtin_amdgcn_mfma_f32_16x16x16bf16_1k)
    return __builtin_amdgcn_mfma_f32_16x16x16bf16_1k(
        __builtin_bit_cast(short4v, a), __builtin_bit_cast(short4v, b), c, 0, 0, 0);
#elif __has_builtin(__builtin_amdgcn_mfma_f32_16x16x16_bf16_1k)
    return __builtin_amdgcn_mfma_f32_16x16x16_bf16_1k(
        __builtin_bit_cast(short4v, a), __builtin_bit_cast(short4v, b), c, 0, 0, 0);
#else
    asm volatile("v_mfma_f32_16x16x16_bf16 %0, %1, %2, %0\n\t"
                 "s_nop 7\n\ts_nop 7\n\ts_nop 1"
                 : "+v"(c) : "v"(a), "v"(b));
    return c;
#endif
}

static __device__ __forceinline__ bf16x8 ldsA(const char* xs, int row, int koff) {
    return *(const bf16x8*)(xs + row * 512 + (koff ^ ((row & 7) << 4)));
}

// ---- precompute kernels ----
__global__ void prep_wqkv(const float* __restrict__ qkv_w, bf16* __restrict__ wt) {
    int idx = blockIdx.x * 256 + threadIdx.x;            // 768*256
    if (idx >= 768 * 256) return;
    int n = idx >> 8, k = idx & 255;
    float v = qkv_w[k * 768 + n];
    if (n < 256) v *= SCALE_Q;                           // fold q-scale
    wt[idx] = (bf16)v;                                   // wt[n][k]
}
__global__ void prep_wproj(const float* __restrict__ proj_w, bf16* __restrict__ wt) {
    int idx = blockIdx.x * 256 + threadIdx.x;            // 256*256
    if (idx >= 256 * 256) return;
    int n = idx >> 8, k = idx & 255;
    wt[idx] = (bf16)proj_w[k * 256 + n];                 // wt[n][k]
}
// sb[h][qp][lane][r]: rel-bias part for q=16qt+(lane&15), key=16kt+4*(lane>>4)+r
// (qp = kt*4+qt). -1e30 for key>=49 (pad); 0 for q>=49 (dead rows).
__global__ void prep_sb(const float* __restrict__ bias_table, const int* __restrict__ rel_index,
                        float* __restrict__ sb) {
    int idx = blockIdx.x * 256 + threadIdx.x;            // 8*4096
    if (idx >= 8 * 4096) return;
    int r    = idx & 3;
    int lane = (idx >> 2) & 63;
    int qp   = (idx >> 8) & 15;
    int h    = idx >> 12;
    int kt = qp >> 2, qt = qp & 3;
    int i = qt * 16 + (lane & 15);
    int j = kt * 16 + (lane >> 4) * 4 + r;
    float v;
    if (j >= NTOK)      v = -1e30f;
    else if (i >= NTOK) v = 0.0f;
    else v = bias_table[rel_index[i * 49 + j] * 8 + h];
    sb[idx] = v;
}
// sm[w][qp][lane][r]: window-mask part (0 on padded rows/cols).
__global__ void prep_sm(const float* __restrict__ mask, float* __restrict__ sm) {
    int idx = blockIdx.x * 256 + threadIdx.x;            // 64*4096
    if (idx >= 64 * 4096) return;
    int r    = idx & 3;
    int lane = (idx >> 2) & 63;
    int qp   = (idx >> 8) & 15;
    int w    = idx >> 12;
    int kt = qp >> 2, qt = qp & 3;
    int i = qt * 16 + (lane & 15);
    int j = kt * 16 + (lane >> 4) * 4 + r;
    sm[idx] = (i < NTOK && j < NTOK) ? mask[(w * 49 + i) * 49 + j] : 0.0f;
}

__global__ __launch_bounds__(512, 3) void fused_attn(
    const float* __restrict__ x,
    const float* __restrict__ qkv_b,
    const float* __restrict__ proj_b,
    const bf16* __restrict__ wt_qkv,
    const bf16* __restrict__ wt_proj,
    const float* __restrict__ sb,
    const float* __restrict__ sm,
    float* __restrict__ out)
{
    __shared__ char xs[32768];       // x tile (bf16, swizzled); later attn-out
    const int b    = blockIdx.x;
    const int tid  = threadIdx.x;
    const int lane = tid & 63;
    const int h    = tid >> 6;       // wave id == head
    const int c    = lane & 15;
    const int g    = lane >> 4;

    // ---- stage x -> xs: 8 reg-loads batched, then cvt+write ----
    {
        const float* xb = x + (size_t)b * (NTOK * 256);
        float4 xr[8];
        #pragma unroll
        for (int it = 0; it < 8; ++it) {
            int idx = it * 512 + tid;          // 64 rows x 64 float4-chunks
            int row = idx >> 6, c4 = idx & 63;
            xr[it] = make_float4(0.f, 0.f, 0.f, 0.f);
            if (row < NTOK) xr[it] = ((const float4*)xb)[row * 64 + c4];
        }
        #pragma unroll
        for (int it = 0; it < 8; ++it) {
            int idx = it * 512 + tid;
            int row = idx >> 6, c4 = idx & 63;
            bf16x4 o;
            o[0] = (bf16)xr[it].x; o[1] = (bf16)xr[it].y;
            o[2] = (bf16)xr[it].z; o[3] = (bf16)xr[it].w;
            *(bf16x4*)(xs + row * 512 + ((c4 * 8) ^ ((row & 7) << 4))) = o;
        }
    }
    __syncthreads();

    // identity B-fragment for the transpose-MFMA: B[k][col] = (k==col)
    bf16x4 iden;
    #pragma unroll
    for (int j = 0; j < 4; ++j) iden[j] = (bf16)((4 * g + j == c) ? 1.0f : 0.0f);

    bf16x4 qf[4][2];   // [qt][ct]  B-frag for scores (dies as qt advances)
    bf16x4 kf[4][2];   // [kt][ct]  A-frag for scores
    bf16x4 pB[4][4];   // [qt][kt]  softmax out == PV B-frag (parks thru V)
    bf16x4 vf[2][4];   // [dt][kt]  A-frag for PV

    // ---- pass Q: BK=32, 2-wide weight batches ----
    {
        f32x4 acc[2][4];
        #pragma unroll
        for (int ni = 0; ni < 2; ++ni)
            #pragma unroll
            for (int mi = 0; mi < 4; ++mi)
                acc[ni][mi] = (f32x4){0.f, 0.f, 0.f, 0.f};
        #pragma unroll
        for (int kk = 0; kk < 8; ++kk) {
            bf16x8 bb[2];
            #pragma unroll
            for (int ni = 0; ni < 2; ++ni)
                bb[ni] = *(const bf16x8*)(wt_qkv + (h * 32 + ni * 16 + c) * 256 + kk * 32 + g * 8);
            bf16x8 a[4];
            #pragma unroll
            for (int mi = 0; mi < 4; ++mi)
                a[mi] = ldsA(xs, mi * 16 + c, kk * 64 + g * 16);
            #pragma unroll
            for (int ni = 0; ni < 2; ++ni)
                #pragma unroll
                for (int mi = 0; mi < 4; ++mi)
                    acc[ni][mi] = __builtin_amdgcn_mfma_f32_16x16x32_bf16(a[mi], bb[ni], acc[ni][mi], 0, 0, 0);
        }
        #pragma unroll
        for (int ni = 0; ni < 2; ++ni) {
            float bias = qkv_b[h * 32 + ni * 16 + c] * SCALE_Q;
            #pragma unroll
            for (int mi = 0; mi < 4; ++mi) {
                bf16x4 in;
                #pragma unroll
                for (int r = 0; r < 4; ++r) in[r] = (bf16)(acc[ni][mi][r] + bias);
                f32x4 t = mfma16(in, iden, (f32x4){0.f, 0.f, 0.f, 0.f});
                #pragma unroll
                for (int r = 0; r < 4; ++r) qf[mi][ni][r] = (bf16)t[r];
            }
        }
    }

    // ---- pass K: BK=32, 2-wide ----
    {
        f32x4 acc[2][4];
        #pragma unroll
        for (int ni = 0; ni < 2; ++ni)
            #pragma unroll
            for (int mi = 0; mi < 4; ++mi)
                acc[ni][mi] = (f32x4){0.f, 0.f, 0.f, 0.f};
        #pragma unroll
        for (int kk = 0; kk < 8; ++kk) {
            bf16x8 bb[2];
            #pragma unroll
            for (int ni = 0; ni < 2; ++ni)
                bb[ni] = *(const bf16x8*)(wt_qkv + (256 + h * 32 + ni * 16 + c) * 256 + kk * 32 + g * 8);
            bf16x8 a[4];
            #pragma unroll
            for (int mi = 0; mi < 4; ++mi)
                a[mi] = ldsA(xs, mi * 16 + c, kk * 64 + g * 16);
            #pragma unroll
            for (int ni = 0; ni < 2; ++ni)
                #pragma unroll
                for (int mi = 0; mi < 4; ++mi)
                    acc[ni][mi] = __builtin_amdgcn_mfma_f32_16x16x32_bf16(a[mi], bb[ni], acc[ni][mi], 0, 0, 0);
        }
        #pragma unroll
        for (int ni = 0; ni < 2; ++ni) {
            float bias = qkv_b[256 + h * 32 + ni * 16 + c];
            #pragma unroll
            for (int mi = 0; mi < 4; ++mi) {
                bf16x4 in;
                #pragma unroll
                for (int r = 0; r < 4; ++r) in[r] = (bf16)(acc[ni][mi][r] + bias);
                f32x4 t = mfma16(in, iden, (f32x4){0.f, 0.f, 0.f, 0.f});
                #pragma unroll
                for (int r = 0; r < 4; ++r) kf[mi][ni][r] = (bf16)t[r];
            }
        }
    }

    // ---- scores + softmax (per qt; sequential sbv/smv adds) ----
    {
        const float* sbh = sb + (size_t)h * 4096;
        const float* smw = sm + (size_t)(b & 63) * 4096;
        #pragma unroll
        for (int qt = 0; qt < 4; ++qt) {
            f32x4 sbv[4];
            #pragma unroll
            for (int kt = 0; kt < 4; ++kt)
                sbv[kt] = *(const f32x4*)(sbh + (kt * 4 + qt) * 256 + lane * 4);

            f32x4 sT[4];
            __builtin_amdgcn_s_setprio(1);
            #pragma unroll
            for (int kt = 0; kt < 4; ++kt) {
                sT[kt] = (f32x4){0.f, 0.f, 0.f, 0.f};
                sT[kt] = mfma16(kf[kt][0], qf[qt][0], sT[kt]);
                sT[kt] = mfma16(kf[kt][1], qf[qt][1], sT[kt]);
            }
            __builtin_amdgcn_s_setprio(0);
            // add bias part first (sbv dies), then mask part
            #pragma unroll
            for (int kt = 0; kt < 4; ++kt)
                #pragma unroll
                for (int r = 0; r < 4; ++r)
                    sT[kt][r] += sbv[kt][r];
            f32x4 smv[4];
            #pragma unroll
            for (int kt = 0; kt < 4; ++kt)
                smv[kt] = *(const f32x4*)(smw + (kt * 4 + qt) * 256 + lane * 4);
            #pragma unroll
            for (int kt = 0; kt < 4; ++kt)
                #pragma unroll
                for (int r = 0; r < 4; ++r)
                    sT[kt][r] += smv[kt][r];
            float m = sT[0][0];
            #pragma unroll
            for (int kt = 0; kt < 4; ++kt)
                #pragma unroll
                for (int r = 0; r < 4; ++r) m = fmaxf(m, sT[kt][r]);
            m = fmaxf(m, __shfl_xor(m, 16));
            m = fmaxf(m, __shfl_xor(m, 32));
            float sum = 0.f;
            #pragma unroll
            for (int kt = 0; kt < 4; ++kt)
                #pragma unroll
                for (int r = 0; r < 4; ++r) {
                    float e = __expf(sT[kt][r] - m);
                    sT[kt][r] = e;
                    sum += e;
                }
            sum += __shfl_xor(sum, 16);
            sum += __shfl_xor(sum, 32);
            float rs = 1.f / sum;
            #pragma unroll
            for (int kt = 0; kt < 4; ++kt)
                #pragma unroll
                for (int r = 0; r < 4; ++r) pB[qt][kt][r] = (bf16)(sT[kt][r] * rs);
        }
    }

    // ---- pass V: two dt half-passes, BK=32 (acc[4]=16; pB 32 parked) ----
    #pragma unroll
    for (int dt = 0; dt < 2; ++dt) {
        f32x4 acc[4];
        #pragma unroll
        for (int mi = 0; mi < 4; ++mi)
            acc[mi] = (f32x4){0.f, 0.f, 0.f, 0.f};
        #pragma unroll
        for (int kk = 0; kk < 8; ++kk) {
            bf16x8 bv = *(const bf16x8*)(wt_qkv + (512 + h * 32 + dt * 16 + c) * 256 + kk * 32 + g * 8);
            bf16x8 a[4];
            #pragma unroll
            for (int mi = 0; mi < 4; ++mi)
                a[mi] = ldsA(xs, mi * 16 + c, kk * 64 + g * 16);
            #pragma unroll
            for (int mi = 0; mi < 4; ++mi)
                acc[mi] = __builtin_amdgcn_mfma_f32_16x16x32_bf16(a[mi], bv, acc[mi], 0, 0, 0);
        }
        float vb = qkv_b[512 + h * 32 + dt * 16 + c];
        #pragma unroll
        for (int kt = 0; kt < 4; ++kt)
            #pragma unroll
            for (int r = 0; r < 4; ++r) vf[dt][kt][r] = (bf16)(acc[kt][r] + vb);
    }
    __syncthreads();   // all xs reads done; xs becomes attn-out buffer

    // ---- PV after barrier: write straight to xs (no ob park) ----
    __builtin_amdgcn_s_setprio(1);
    #pragma unroll
    for (int qt = 0; qt < 4; ++qt) {
        int row = qt * 16 + c;
        #pragma unroll
        for (int dt = 0; dt < 2; ++dt) {
            f32x4 oT = (f32x4){0.f, 0.f, 0.f, 0.f};
            #pragma unroll
            for (int kt = 0; kt < 4; ++kt)
                oT = mfma16(vf[dt][kt], pB[qt][kt], oT);
            int cbyte = h * 64 + dt * 32 + g * 8;
            bf16x4 o;
            #pragma unroll
            for (int r = 0; r < 4; ++r) o[r] = (bf16)oT[r];
            *(bf16x4*)(xs + row * 512 + (cbyte ^ ((row & 7) << 4))) = o;
        }
    }
    __builtin_amdgcn_s_setprio(0);
    __syncthreads();

    // ---- proj: BK=64, 4-wide weight batches ----
    {
        f32x4 po[2][4];
        #pragma unroll
        for (int ni = 0; ni < 2; ++ni)
            #pragma unroll
            for (int mi = 0; mi < 4; ++mi)
                po[ni][mi] = (f32x4){0.f, 0.f, 0.f, 0.f};

        #pragma unroll
        for (int k2 = 0; k2 < 4; ++k2) {
            bf16x8 bw[2][2];
            #pragma unroll
            for (int ni = 0; ni < 2; ++ni)
                #pragma unroll
                for (int hf = 0; hf < 2; ++hf)
                    bw[ni][hf] = *(const bf16x8*)(wt_proj + (h * 32 + ni * 16 + c) * 256
                                                  + k2 * 64 + hf * 32 + g * 8);
            bf16x8 a[2][4];
            #pragma unroll
            for (int hf = 0; hf < 2; ++hf)
                #pragma unroll
                for (int mi = 0; mi < 4; ++mi)
                    a[hf][mi] = ldsA(xs, mi * 16 + c, k2 * 128 + hf * 64 + g * 16);
            #pragma unroll
            for (int hf = 0; hf < 2; ++hf)
                #pragma unroll
                for (int ni = 0; ni < 2; ++ni)
                    #pragma unroll
                    for (int mi = 0; mi < 4; ++mi)
                        po[ni][mi] = __builtin_amdgcn_mfma_f32_16x16x32_bf16(a[hf][mi], bw[ni][hf], po[ni][mi], 0, 0, 0);
        }
        float* outb = out + (size_t)b * (NTOK * 256);
        #pragma unroll
        for (int ni = 0; ni < 2; ++ni) {
            int col = h * 32 + ni * 16 + c;
            float pb = proj_b[col];
            #pragma unroll
            for (int mi = 0; mi < 4; ++mi) {
                #pragma unroll
                for (int r = 0; r < 4; ++r) {
                    int row = mi * 16 + g * 4 + r;
                    if (row < NTOK) outb[row * 256 + col] = po[ni][mi][r] + pb;
                }
            }
        }
    }
}

extern "C" void kernel_launch(void* const* d_in, const int* in_sizes, int n_in,
                              void* d_out, int out_size, void* d_ws, size_t ws_size,
                              hipStream_t stream) {
    const float* x          = (const float*)d_in[0];
    const float* mask       = (const float*)d_in[1];
    const float* qkv_w      = (const float*)d_in[2];
    const float* qkv_b      = (const float*)d_in[3];
    const float* proj_w     = (const float*)d_in[4];
    const float* proj_b     = (const float*)d_in[5];
    const float* bias_table = (const float*)d_in[6];
    const int*   rel_index  = (const int*)d_in[7];
    float* out = (float*)d_out;

    if (ws_size < WS_NEEDED) return;  // needs ~1.7 MB scratch

    char* ws = (char*)d_ws;
    bf16*  wt_qkv  = (bf16*)(ws + WT_QKV_OFF);
    bf16*  wt_proj = (bf16*)(ws + WT_PROJ_OFF);
    float* sbp     = (float*)(ws + SB_OFF);
    float* smp     = (float*)(ws + SM_OFF);

    prep_wqkv <<<768, 256, 0, stream>>>(qkv_w, wt_qkv);
    prep_wproj<<<256, 256, 0, stream>>>(proj_w, wt_proj);
    prep_sb   <<<128, 256, 0, stream>>>(bias_table, rel_index, sbp);
    prep_sm   <<<1024, 256, 0, stream>>>(mask, smp);

    fused_attn<<<4096, 512, 0, stream>>>(x, qkv_b, proj_b, wt_qkv, wt_proj, sbp, smp, out);
}

// Round 12
// 347.638 us; speedup vs baseline: 1.0834x; 1.0834x over previous
//
#include <hip/hip_runtime.h>
#include <hip/hip_bf16.h>

// ---------------------------------------------------------------------------
// Swin WindowAttention fused kernel, v12 = v10 + xs2 double-buffer.
//   - attn-out goes to a SECOND 32K LDS buffer (xs2): no WAR vs xs, so the
//     ob register park (16) and one full barrier are eliminated. 2 barriers
//     total (post-stage, pre-proj). LDS 64K x 2 blocks = 128K <= 160K.
//   - HW law (R11): waves/SIMD quantized {8,4,2} at VGPR {<=64,<=128,<=256};
//     this op can't fit 64 -> 4 waves/SIMD is the TLP ceiling. Stay 65-128.
//   - v10 kept: depth-2 pipeline in all 4 GEMM passes + cross-phase prefetch
//     (Q tail->K(0), scores tail->V(0), post-PV->proj B(0)); BK=64; 1 head/
//     wave; identity-MFMA transposes; swapped-operand scores; K=16 PV; sb/sm
//     split tables; setprio on attn MFMAs; launch_bounds(512,2).
//   - softmax max/sum as 4-deep trees (was 15-deep serial chains).
// ---------------------------------------------------------------------------

#define NTOK 49
static constexpr float SCALE_Q = 0.17677669529663687f; // 32^-0.5

using bf16   = __bf16;
using bf16x4 = __attribute__((ext_vector_type(4))) __bf16;
using bf16x8 = __attribute__((ext_vector_type(8))) __bf16;
using short4v = __attribute__((ext_vector_type(4))) short;
using f32x4  = __attribute__((ext_vector_type(4))) float;

#define WT_QKV_OFF 0
#define WT_PROJ_OFF (768 * 256 * 2)
#define SB_OFF (WT_PROJ_OFF + 256 * 256 * 2)
#define SM_OFF (SB_OFF + 8 * 4096 * 4)
#define WS_NEEDED (SM_OFF + (size_t)64 * 4096 * 4)

// ---- 16x16x16 bf16 MFMA wrapper (builtin-name portability) ----
static __device__ __forceinline__ f32x4 mfma16(bf16x4 a, bf16x4 b, f32x4 c) {
#if __has_builtin(__builtin_amdgcn_mfma_f32_16x16x16_bf16)
    return __builtin_amdgcn_mfma_f32_16x16x16_bf16(a, b, c, 0, 0, 0);
#elif __has_builtin(__builtin_amdgcn_mfma_f32_16x16x16bf16_1k)
    return __builtin_amdgcn_mfma_f32_16x16x16bf16_1k(
        __builtin_bit_cast(short4v, a), __builtin_bit_cast(short4v, b), c, 0, 0, 0);
#elif __has_builtin(__builtin_amdgcn_mfma_f32_16x16x16_bf16_1k)
    return __builtin_amdgcn_mfma_f32_16x16x16_bf16_1k(
        __builtin_bit_cast(short4v, a), __builtin_bit_cast(short4v, b), c, 0, 0, 0);
#else
    asm volatile("v_mfma_f32_16x16x16_bf16 %0, %1, %2, %0\n\t"
                 "s_nop 7\n\ts_nop 7\n\ts_nop 1"
                 : "+v"(c) : "v"(a), "v"(b));
    return c;
#endif
}

static __device__ __forceinline__ bf16x8 ldsA(const char* base, int row, int koff) {
    return *(const bf16x8*)(base + row * 512 + (koff ^ ((row & 7) << 4)));
}
static __device__ __forceinline__ bf16x8 ldB(const bf16* wt, int ncol, int k2, int hf, int g) {
    return *(const bf16x8*)(wt + ncol * 256 + k2 * 64 + hf * 32 + g * 8);
}

// ---- precompute kernels ----
__global__ void prep_wqkv(const float* __restrict__ qkv_w, bf16* __restrict__ wt) {
    int idx = blockIdx.x * 256 + threadIdx.x;            // 768*256
    if (idx >= 768 * 256) return;
    int n = idx >> 8, k = idx & 255;
    float v = qkv_w[k * 768 + n];
    if (n < 256) v *= SCALE_Q;                           // fold q-scale
    wt[idx] = (bf16)v;                                   // wt[n][k]
}
__global__ void prep_wproj(const float* __restrict__ proj_w, bf16* __restrict__ wt) {
    int idx = blockIdx.x * 256 + threadIdx.x;            // 256*256
    if (idx >= 256 * 256) return;
    int n = idx >> 8, k = idx & 255;
    wt[idx] = (bf16)proj_w[k * 256 + n];                 // wt[n][k]
}
// sb[h][qp][lane][r]: rel-bias part for q=16qt+(lane&15), key=16kt+4*(lane>>4)+r
// (qp = kt*4+qt). -1e30 for key>=49 (pad); 0 for q>=49 (dead rows).
__global__ void prep_sb(const float* __restrict__ bias_table, const int* __restrict__ rel_index,
                        float* __restrict__ sb) {
    int idx = blockIdx.x * 256 + threadIdx.x;            // 8*4096
    if (idx >= 8 * 4096) return;
    int r    = idx & 3;
    int lane = (idx >> 2) & 63;
    int qp   = (idx >> 8) & 15;
    int h    = idx >> 12;
    int kt = qp >> 2, qt = qp & 3;
    int i = qt * 16 + (lane & 15);
    int j = kt * 16 + (lane >> 4) * 4 + r;
    float v;
    if (j >= NTOK)      v = -1e30f;
    else if (i >= NTOK) v = 0.0f;
    else v = bias_table[rel_index[i * 49 + j] * 8 + h];
    sb[idx] = v;
}
// sm[w][qp][lane][r]: window-mask part (0 on padded rows/cols).
__global__ void prep_sm(const float* __restrict__ mask, float* __restrict__ sm) {
    int idx = blockIdx.x * 256 + threadIdx.x;            // 64*4096
    if (idx >= 64 * 4096) return;
    int r    = idx & 3;
    int lane = (idx >> 2) & 63;
    int qp   = (idx >> 8) & 15;
    int w    = idx >> 12;
    int kt = qp >> 2, qt = qp & 3;
    int i = qt * 16 + (lane & 15);
    int j = kt * 16 + (lane >> 4) * 4 + r;
    sm[idx] = (i < NTOK && j < NTOK) ? mask[(w * 49 + i) * 49 + j] : 0.0f;
}

__global__ __launch_bounds__(512, 2) void fused_attn(
    const float* __restrict__ x,
    const float* __restrict__ qkv_b,
    const float* __restrict__ proj_b,
    const bf16* __restrict__ wt_qkv,
    const bf16* __restrict__ wt_proj,
    const float* __restrict__ sb,
    const float* __restrict__ sm,
    float* __restrict__ out)
{
    __shared__ char smem[65536];
    char* xs  = smem;            // x tile (bf16, swizzled)
    char* xs2 = smem + 32768;    // attn-out tile (bf16, swizzled)
    const int b    = blockIdx.x;
    const int tid  = threadIdx.x;
    const int lane = tid & 63;
    const int h    = tid >> 6;       // wave id == head
    const int c    = lane & 15;
    const int g    = lane >> 4;

    // ---- stage x -> xs: 8 reg-loads batched, then cvt+write ----
    {
        const float* xb = x + (size_t)b * (NTOK * 256);
        float4 xr[8];
        #pragma unroll
        for (int it = 0; it < 8; ++it) {
            int idx = it * 512 + tid;          // 64 rows x 64 float4-chunks
            int row = idx >> 6, c4 = idx & 63;
            xr[it] = make_float4(0.f, 0.f, 0.f, 0.f);
            if (row < NTOK) xr[it] = ((const float4*)xb)[row * 64 + c4];
        }
        #pragma unroll
        for (int it = 0; it < 8; ++it) {
            int idx = it * 512 + tid;
            int row = idx >> 6, c4 = idx & 63;
            bf16x4 o;
            o[0] = (bf16)xr[it].x; o[1] = (bf16)xr[it].y;
            o[2] = (bf16)xr[it].z; o[3] = (bf16)xr[it].w;
            *(bf16x4*)(xs + row * 512 + ((c4 * 8) ^ ((row & 7) << 4))) = o;
        }
    }
    __syncthreads();

    // identity B-fragment for the transpose-MFMA: B[k][col] = (k==col)
    bf16x4 iden;
    #pragma unroll
    for (int j = 0; j < 4; ++j) iden[j] = (bf16)((4 * g + j == c) ? 1.0f : 0.0f);

    bf16x4 qf[4][2];   // [qt][ct]  B-frag for scores (dies as qt advances)
    bf16x4 kf[4][2];   // [kt][ct]  A-frag for scores
    bf16x4 pB[4][4];   // [qt][kt]  softmax out == PV B-frag (parks thru V)
    bf16x4 vf[2][4];   // [dt][kt]  A-frag for PV

    const int colQ = h * 32 + c;          // +0 / +16 for ni
    const int colK = 256 + h * 32 + c;
    const int colV = 512 + h * 32 + c;

    // pipeline registers
    bf16x8 bcur[2][2], bnxt[2][2];        // [ni][hf]
    bf16x8 acur[2][4], anxt[2][4];        // [hf][mi]

    // ---- preload Q(k2=0) ----
    #pragma unroll
    for (int ni = 0; ni < 2; ++ni)
        #pragma unroll
        for (int hf = 0; hf < 2; ++hf)
            bcur[ni][hf] = ldB(wt_qkv, colQ + ni * 16, 0, hf, g);
    #pragma unroll
    for (int hf = 0; hf < 2; ++hf)
        #pragma unroll
        for (int mi = 0; mi < 4; ++mi)
            acur[hf][mi] = ldsA(xs, mi * 16 + c, hf * 64 + g * 16);

    // ---- pass Q (pipelined; tail prefetches K(0)) ----
    {
        f32x4 acc[2][4];
        #pragma unroll
        for (int ni = 0; ni < 2; ++ni)
            #pragma unroll
            for (int mi = 0; mi < 4; ++mi)
                acc[ni][mi] = (f32x4){0.f, 0.f, 0.f, 0.f};
        #pragma unroll
        for (int k2 = 0; k2 < 4; ++k2) {
            if (k2 < 3) {
                #pragma unroll
                for (int ni = 0; ni < 2; ++ni)
                    #pragma unroll
                    for (int hf = 0; hf < 2; ++hf)
                        bnxt[ni][hf] = ldB(wt_qkv, colQ + ni * 16, k2 + 1, hf, g);
                #pragma unroll
                for (int hf = 0; hf < 2; ++hf)
                    #pragma unroll
                    for (int mi = 0; mi < 4; ++mi)
                        anxt[hf][mi] = ldsA(xs, mi * 16 + c, (k2 + 1) * 128 + hf * 64 + g * 16);
            } else {   // cross-phase: K's k2=0
                #pragma unroll
                for (int ni = 0; ni < 2; ++ni)
                    #pragma unroll
                    for (int hf = 0; hf < 2; ++hf)
                        bnxt[ni][hf] = ldB(wt_qkv, colK + ni * 16, 0, hf, g);
                #pragma unroll
                for (int hf = 0; hf < 2; ++hf)
                    #pragma unroll
                    for (int mi = 0; mi < 4; ++mi)
                        anxt[hf][mi] = ldsA(xs, mi * 16 + c, hf * 64 + g * 16);
            }
            #pragma unroll
            for (int hf = 0; hf < 2; ++hf)
                #pragma unroll
                for (int ni = 0; ni < 2; ++ni)
                    #pragma unroll
                    for (int mi = 0; mi < 4; ++mi)
                        acc[ni][mi] = __builtin_amdgcn_mfma_f32_16x16x32_bf16(acur[hf][mi], bcur[ni][hf], acc[ni][mi], 0, 0, 0);
            #pragma unroll
            for (int ni = 0; ni < 2; ++ni)
                #pragma unroll
                for (int hf = 0; hf < 2; ++hf)
                    bcur[ni][hf] = bnxt[ni][hf];
            #pragma unroll
            for (int hf = 0; hf < 2; ++hf)
                #pragma unroll
                for (int mi = 0; mi < 4; ++mi)
                    acur[hf][mi] = anxt[hf][mi];
        }
        #pragma unroll
        for (int ni = 0; ni < 2; ++ni) {
            float bias = qkv_b[h * 32 + ni * 16 + c] * SCALE_Q;
            #pragma unroll
            for (int mi = 0; mi < 4; ++mi) {
                bf16x4 in;
                #pragma unroll
                for (int r = 0; r < 4; ++r) in[r] = (bf16)(acc[ni][mi][r] + bias);
                f32x4 t = mfma16(in, iden, (f32x4){0.f, 0.f, 0.f, 0.f});
                #pragma unroll
                for (int r = 0; r < 4; ++r) qf[mi][ni][r] = (bf16)t[r];
            }
        }
    }

    // ---- pass K (pipelined; bcur/acur hold K(0) already) ----
    {
        f32x4 acc[2][4];
        #pragma unroll
        for (int ni = 0; ni < 2; ++ni)
            #pragma unroll
            for (int mi = 0; mi < 4; ++mi)
                acc[ni][mi] = (f32x4){0.f, 0.f, 0.f, 0.f};
        #pragma unroll
        for (int k2 = 0; k2 < 4; ++k2) {
            if (k2 < 3) {
                #pragma unroll
                for (int ni = 0; ni < 2; ++ni)
                    #pragma unroll
                    for (int hf = 0; hf < 2; ++hf)
                        bnxt[ni][hf] = ldB(wt_qkv, colK + ni * 16, k2 + 1, hf, g);
                #pragma unroll
                for (int hf = 0; hf < 2; ++hf)
                    #pragma unroll
                    for (int mi = 0; mi < 4; ++mi)
                        anxt[hf][mi] = ldsA(xs, mi * 16 + c, (k2 + 1) * 128 + hf * 64 + g * 16);
            }
            #pragma unroll
            for (int hf = 0; hf < 2; ++hf)
                #pragma unroll
                for (int ni = 0; ni < 2; ++ni)
                    #pragma unroll
                    for (int mi = 0; mi < 4; ++mi)
                        acc[ni][mi] = __builtin_amdgcn_mfma_f32_16x16x32_bf16(acur[hf][mi], bcur[ni][hf], acc[ni][mi], 0, 0, 0);
            if (k2 < 3) {
                #pragma unroll
                for (int ni = 0; ni < 2; ++ni)
                    #pragma unroll
                    for (int hf = 0; hf < 2; ++hf)
                        bcur[ni][hf] = bnxt[ni][hf];
                #pragma unroll
                for (int hf = 0; hf < 2; ++hf)
                    #pragma unroll
                    for (int mi = 0; mi < 4; ++mi)
                        acur[hf][mi] = anxt[hf][mi];
            }
        }
        #pragma unroll
        for (int ni = 0; ni < 2; ++ni) {
            float bias = qkv_b[256 + h * 32 + ni * 16 + c];
            #pragma unroll
            for (int mi = 0; mi < 4; ++mi) {
                bf16x4 in;
                #pragma unroll
                for (int r = 0; r < 4; ++r) in[r] = (bf16)(acc[ni][mi][r] + bias);
                f32x4 t = mfma16(in, iden, (f32x4){0.f, 0.f, 0.f, 0.f});
                #pragma unroll
                for (int r = 0; r < 4; ++r) kf[mi][ni][r] = (bf16)t[r];
            }
        }
    }

    // ---- scores + softmax (per qt; last qt prefetches V(0)) ----
    {
        const float* sbh = sb + (size_t)h * 4096;
        const float* smw = sm + (size_t)(b & 63) * 4096;
        #pragma unroll
        for (int qt = 0; qt < 4; ++qt) {
            f32x4 sbv[4], smv[4];
            #pragma unroll
            for (int kt = 0; kt < 4; ++kt)
                sbv[kt] = *(const f32x4*)(sbh + (kt * 4 + qt) * 256 + lane * 4);
            #pragma unroll
            for (int kt = 0; kt < 4; ++kt)
                smv[kt] = *(const f32x4*)(smw + (kt * 4 + qt) * 256 + lane * 4);

            f32x4 sT[4];
            __builtin_amdgcn_s_setprio(1);
            #pragma unroll
            for (int kt = 0; kt < 4; ++kt) {
                sT[kt] = (f32x4){0.f, 0.f, 0.f, 0.f};
                sT[kt] = mfma16(kf[kt][0], qf[qt][0], sT[kt]);
                sT[kt] = mfma16(kf[kt][1], qf[qt][1], sT[kt]);
            }
            __builtin_amdgcn_s_setprio(0);
            if (qt == 3) {   // prefetch V's k2=0 under the softmax tail
                #pragma unroll
                for (int ni = 0; ni < 2; ++ni)
                    #pragma unroll
                    for (int hf = 0; hf < 2; ++hf)
                        bcur[ni][hf] = ldB(wt_qkv, colV + ni * 16, 0, hf, g);
                #pragma unroll
                for (int hf = 0; hf < 2; ++hf)
                    #pragma unroll
                    for (int mi = 0; mi < 4; ++mi)
                        acur[hf][mi] = ldsA(xs, mi * 16 + c, hf * 64 + g * 16);
            }
            #pragma unroll
            for (int kt = 0; kt < 4; ++kt)
                #pragma unroll
                for (int r = 0; r < 4; ++r)
                    sT[kt][r] += sbv[kt][r] + smv[kt][r];
            // tree max over the 16 in-lane values, then cross-lane
            f32x4 mx4;
            #pragma unroll
            for (int r = 0; r < 4; ++r)
                mx4[r] = fmaxf(fmaxf(sT[0][r], sT[1][r]), fmaxf(sT[2][r], sT[3][r]));
            float m = fmaxf(fmaxf(mx4[0], mx4[1]), fmaxf(mx4[2], mx4[3]));
            m = fmaxf(m, __shfl_xor(m, 16));
            m = fmaxf(m, __shfl_xor(m, 32));
            f32x4 sm4 = (f32x4){0.f, 0.f, 0.f, 0.f};
            #pragma unroll
            for (int kt = 0; kt < 4; ++kt)
                #pragma unroll
                for (int r = 0; r < 4; ++r) {
                    float e = __expf(sT[kt][r] - m);
                    sT[kt][r] = e;
                    sm4[r] += e;
                }
            float sum = (sm4[0] + sm4[1]) + (sm4[2] + sm4[3]);
            sum += __shfl_xor(sum, 16);
            sum += __shfl_xor(sum, 32);
            float rs = 1.f / sum;
            #pragma unroll
            for (int kt = 0; kt < 4; ++kt)
                #pragma unroll
                for (int r = 0; r < 4; ++r) pB[qt][kt][r] = (bf16)(sT[kt][r] * rs);
        }
    }

    // ---- pass V (pipelined; bcur/acur hold V(0)) ----
    {
        f32x4 acc[2][4];
        #pragma unroll
        for (int dt = 0; dt < 2; ++dt)
            #pragma unroll
            for (int mi = 0; mi < 4; ++mi)
                acc[dt][mi] = (f32x4){0.f, 0.f, 0.f, 0.f};
        #pragma unroll
        for (int k2 = 0; k2 < 4; ++k2) {
            if (k2 < 3) {
                #pragma unroll
                for (int dt = 0; dt < 2; ++dt)
                    #pragma unroll
                    for (int hf = 0; hf < 2; ++hf)
                        bnxt[dt][hf] = ldB(wt_qkv, colV + dt * 16, k2 + 1, hf, g);
                #pragma unroll
                for (int hf = 0; hf < 2; ++hf)
                    #pragma unroll
                    for (int mi = 0; mi < 4; ++mi)
                        anxt[hf][mi] = ldsA(xs, mi * 16 + c, (k2 + 1) * 128 + hf * 64 + g * 16);
            }
            #pragma unroll
            for (int hf = 0; hf < 2; ++hf)
                #pragma unroll
                for (int dt = 0; dt < 2; ++dt)
                    #pragma unroll
                    for (int mi = 0; mi < 4; ++mi)
                        acc[dt][mi] = __builtin_amdgcn_mfma_f32_16x16x32_bf16(acur[hf][mi], bcur[dt][hf], acc[dt][mi], 0, 0, 0);
            if (k2 < 3) {
                #pragma unroll
                for (int dt = 0; dt < 2; ++dt)
                    #pragma unroll
                    for (int hf = 0; hf < 2; ++hf)
                        bcur[dt][hf] = bnxt[dt][hf];
                #pragma unroll
                for (int hf = 0; hf < 2; ++hf)
                    #pragma unroll
                    for (int mi = 0; mi < 4; ++mi)
                        acur[hf][mi] = anxt[hf][mi];
            }
        }
        #pragma unroll
        for (int dt = 0; dt < 2; ++dt) {
            float vb = qkv_b[512 + h * 32 + dt * 16 + c];
            #pragma unroll
            for (int kt = 0; kt < 4; ++kt)
                #pragma unroll
                for (int r = 0; r < 4; ++r) vf[dt][kt][r] = (bf16)(acc[dt][kt][r] + vb);
        }
    }

    // ---- PV: write straight to xs2 (no WAR vs xs; no ob park) ----
    __builtin_amdgcn_s_setprio(1);
    #pragma unroll
    for (int qt = 0; qt < 4; ++qt) {
        int row = qt * 16 + c;
        #pragma unroll
        for (int dt = 0; dt < 2; ++dt) {
            f32x4 oT = (f32x4){0.f, 0.f, 0.f, 0.f};
            #pragma unroll
            for (int kt = 0; kt < 4; ++kt)
                oT = mfma16(vf[dt][kt], pB[qt][kt], oT);
            int cbyte = h * 64 + dt * 32 + g * 8;
            bf16x4 o;
            #pragma unroll
            for (int r = 0; r < 4; ++r) o[r] = (bf16)oT[r];
            *(bf16x4*)(xs2 + row * 512 + (cbyte ^ ((row & 7) << 4))) = o;
        }
    }
    __builtin_amdgcn_s_setprio(0);

    // prefetch proj's B(0) before the barrier (global load, no LDS dep)
    #pragma unroll
    for (int ni = 0; ni < 2; ++ni)
        #pragma unroll
        for (int hf = 0; hf < 2; ++hf)
            bcur[ni][hf] = ldB(wt_proj, h * 32 + ni * 16 + c, 0, hf, g);

    __syncthreads();   // single barrier: all PV writes to xs2 visible

    // ---- proj (pipelined; bcur holds proj(0); A from xs2) ----
    {
        f32x4 po[2][4];
        #pragma unroll
        for (int ni = 0; ni < 2; ++ni)
            #pragma unroll
            for (int mi = 0; mi < 4; ++mi)
                po[ni][mi] = (f32x4){0.f, 0.f, 0.f, 0.f};

        #pragma unroll
        for (int hf = 0; hf < 2; ++hf)
            #pragma unroll
            for (int mi = 0; mi < 4; ++mi)
                acur[hf][mi] = ldsA(xs2, mi * 16 + c, hf * 64 + g * 16);

        #pragma unroll
        for (int k2 = 0; k2 < 4; ++k2) {
            if (k2 < 3) {
                #pragma unroll
                for (int ni = 0; ni < 2; ++ni)
                    #pragma unroll
                    for (int hf = 0; hf < 2; ++hf)
                        bnxt[ni][hf] = ldB(wt_proj, h * 32 + ni * 16 + c, k2 + 1, hf, g);
                #pragma unroll
                for (int hf = 0; hf < 2; ++hf)
                    #pragma unroll
                    for (int mi = 0; mi < 4; ++mi)
                        anxt[hf][mi] = ldsA(xs2, mi * 16 + c, (k2 + 1) * 128 + hf * 64 + g * 16);
            }
            #pragma unroll
            for (int hf = 0; hf < 2; ++hf)
                #pragma unroll
                for (int ni = 0; ni < 2; ++ni)
                    #pragma unroll
                    for (int mi = 0; mi < 4; ++mi)
                        po[ni][mi] = __builtin_amdgcn_mfma_f32_16x16x32_bf16(acur[hf][mi], bcur[ni][hf], po[ni][mi], 0, 0, 0);
            if (k2 < 3) {
                #pragma unroll
                for (int ni = 0; ni < 2; ++ni)
                    #pragma unroll
                    for (int hf = 0; hf < 2; ++hf)
                        bcur[ni][hf] = bnxt[ni][hf];
                #pragma unroll
                for (int hf = 0; hf < 2; ++hf)
                    #pragma unroll
                    for (int mi = 0; mi < 4; ++mi)
                        acur[hf][mi] = anxt[hf][mi];
            }
        }
        float* outb = out + (size_t)b * (NTOK * 256);
        #pragma unroll
        for (int ni = 0; ni < 2; ++ni) {
            int col = h * 32 + ni * 16 + c;
            float pb = proj_b[col];
            #pragma unroll
            for (int mi = 0; mi < 4; ++mi) {
                #pragma unroll
                for (int r = 0; r < 4; ++r) {
                    int row = mi * 16 + g * 4 + r;
                    if (row < NTOK) outb[row * 256 + col] = po[ni][mi][r] + pb;
                }
            }
        }
    }
}

extern "C" void kernel_launch(void* const* d_in, const int* in_sizes, int n_in,
                              void* d_out, int out_size, void* d_ws, size_t ws_size,
                              hipStream_t stream) {
    const float* x          = (const float*)d_in[0];
    const float* mask       = (const float*)d_in[1];
    const float* qkv_w      = (const float*)d_in[2];
    const float* qkv_b      = (const float*)d_in[3];
    const float* proj_w     = (const float*)d_in[4];
    const float* proj_b     = (const float*)d_in[5];
    const float* bias_table = (const float*)d_in[6];
    const int*   rel_index  = (const int*)d_in[7];
    float* out = (float*)d_out;

    if (ws_size < WS_NEEDED) return;  // needs ~1.7 MB scratch

    char* ws = (char*)d_ws;
    bf16*  wt_qkv  = (bf16*)(ws + WT_QKV_OFF);
    bf16*  wt_proj = (bf16*)(ws + WT_PROJ_OFF);
    float* sbp     = (float*)(ws + SB_OFF);
    float* smp     = (float*)(ws + SM_OFF);

    prep_wqkv <<<768, 256, 0, stream>>>(qkv_w, wt_qkv);
    prep_wproj<<<256, 256, 0, stream>>>(proj_w, wt_proj);
    prep_sb   <<<128, 256, 0, stream>>>(bias_table, rel_index, sbp);
    prep_sm   <<<1024, 256, 0, stream>>>(mask, smp);

    fused_attn<<<4096, 512, 0, stream>>>(x, qkv_b, proj_b, wt_qkv, wt_proj, sbp, smp, out);
}